// Round 3
// baseline (116.659 us; speedup 1.0000x reference)
//
#include <hip/hip_runtime.h>
#include <cstdint>
#include <cstddef>

#define BB 16
#define NN 4096
#define CC 80
#define MAXD 100
#define CONF_T 0.5f
#define PER_B (MAXD * 4 + MAXD * CC)   // 8400 output elems per batch
#define NWORDS 64                      // 4096/64 bitmap words (fallback)
#define FBCAP 2048                     // fallback kernel's capacity
#define SEGSZ 2048
#define CH 1024                        // lazy-refill chunk (1 entry/thread)
#define TK 256                         // per-round take size (4 mask words)
#define CCAP 1280                      // clean-list cap: 255 leftover + 1024 chunk

// fl32(inter/uni) > 0.5  <=>  inter > uni*(0.5+2^-25), evaluated EXACTLY in
// fp64 (24-bit x 25-bit mantissa product = 49 bits < 53). Bit-identical to
// the reference's IEEE divide + compare. (verified passing rounds 9)
#define IOUC 0x1.000001p-1

// ---- workspace layout ----
#define WS_KEYS   0x000000             // [B*N] u64
#define WS_NEED   0x200000             // 2 MB

// ---------------------------------------------------------------------------
// K1: softmax of (10x)^2 per row — 8 LANES per row, all-register, no LDS.
// Lane j owns elements {j, j+8, ..., j+72}: exactly the numpy pairwise-8
// groups, so the sequential per-lane accumulation == r8[j] chain bitwise.
// Cross-lane max: fmaxf commutative/associative over finite z>=0. Cross-lane
// sum: shfl_xor tree == ((r0+r1)+(r2+r3))+((r4+r5)+(r6+r7)) bitwise.
// (verified passing round 2)
// ---------------------------------------------------------------------------
__global__ __launch_bounds__(256) void k_softmax(const float* __restrict__ cls_in,
                                                 float* __restrict__ probs,
                                                 uint64_t* __restrict__ keys) {
#pragma clang fp contract(off)
    int slot = blockIdx.x * 256 + threadIdx.x;   // 8 slots per row
    int row  = slot >> 3;                        // [0, B*N)
    int j    = slot & 7;
    const float* rp = cls_in + (size_t)row * CC + j;

    float e[10];
    float m = -3.402823466e+38f;
    #pragma unroll
    for (int k = 0; k < 10; ++k) {
        float y = rp[8 * k] * 10.0f;
        float z = y * y;
        e[k] = z;
        m = fmaxf(m, z);
    }
    m = fmaxf(m, __shfl_xor(m, 1));
    m = fmaxf(m, __shfl_xor(m, 2));
    m = fmaxf(m, __shfl_xor(m, 4));

    #pragma unroll
    for (int k = 0; k < 10; ++k) e[k] = expf(e[k] - m);

    float acc = e[0];
    #pragma unroll
    for (int k = 1; k < 10; ++k) acc += e[k];    // r8[j] sequential chain
    acc = acc + __shfl_xor(acc, 1);              // (r0+r1) ...
    acc = acc + __shfl_xor(acc, 2);              // (r0+r1)+(r2+r3) ...
    acc = acc + __shfl_xor(acc, 4);              // full pairwise tree

    float score = 1.0f / acc;
    float* pp = probs + (size_t)row * CC + j;
    #pragma unroll
    for (int k = 0; k < 10; ++k) pp[8 * k] = e[k] * score;

    if (j == 0) {
        unsigned n = (unsigned)(row & (NN - 1));
        keys[row] = ((uint64_t)__float_as_uint(score) << 32)
                  | (uint64_t)(0xFFFFFFFFu - n);
    }
}

// ---------------------------------------------------------------------------
// K2 (fused): partition + rank-sort + LDS corner build + LAZY-LIST NMS (256-
// wide rounds) + fused output gather. One block (1024 thr = 16 waves)/batch.
//
// Clean list C holds, in ascending sorted order, all live candidates with
// position < cursor, each already vetted vs every keep so far. Per round:
//   refill: while |C|<256 and raw left, filter next 1024 raw vs ALL keeps
//           (staged ky* arrays, wave-uniform broadcast reads), stable-append
//   select: C[0..st), st=min(cc,256) = st lowest live overall; stage corners
//   kill matrix 256x256: lane caches its 4 col boxes in regs; 16 rows/wave
//   exact greedy replay over 4 mask words (wave0, branchless OR pipeline);
//           wave0 stages kept corners into ky*[] for the broadcast filters
//   refilter C[st..cc) vs NEW keeps only, stable-compact to front
// done <=> kept>=100 or cc<256 (raw exhausted => everything consumed).
// Identical greedy order to the reference (keeps appended in ascending
// sorted position; 100-prefix stable).
// ---------------------------------------------------------------------------
__global__ __launch_bounds__(1024) void k_pnms(const uint64_t* __restrict__ keys,
                                               const float* __restrict__ boxes,
                                               const float* __restrict__ probs,
                                               float* __restrict__ out_box,
                                               float* __restrict__ out_cls) {
#pragma clang fp contract(off)
    __shared__ __align__(16) unsigned char sraw[6 * NN * 4];   // 96 KB
    float* hy1 = (float*)sraw;
    float* hx1 = (float*)(sraw + NN * 4);
    float* hy2 = (float*)(sraw + 2 * NN * 4);
    float* hx2 = (float*)(sraw + 3 * NN * 4);
    float* har = (float*)(sraw + 4 * NN * 4);
    int*   og  = (int*)(sraw + 5 * NN * 4);
    uint64_t* bbuf = (uint64_t*)sraw;          // overlays hy1+hx1 (32 KB); dead after sort
    __shared__ int clist[CCAP];
    __shared__ uint64_t kill4[TK][4];          // 8 KB: kill4[t][w] = "t kills 64w+lane"
    __shared__ int cand_s[TK];
    __shared__ float scy1[TK], scx1[TK], scy2[TK], scx2[TK], scar[TK];  // staged cands
    __shared__ float ky1[MAXD], kx1[MAXD], ky2[MAXD], kx2[MAXD], kar[MAXD]; // staged keeps
    __shared__ int kpos[MAXD];
    __shared__ int wsumA[16], wsumB[16], wsumC[16];
    __shared__ int kept_s, fk0_s, done_s, ccnt_s, cur_s;

    const int tid = threadIdx.x, lane = tid & 63, wv = tid >> 6;
    const int b = blockIdx.x;
    const uint64_t* kb = keys + (size_t)b * NN;
    const float* bxp = boxes + (size_t)b * NN * 4;

    // ---- partition (og/bbuf in LDS, keys untouched) ----
    uint64_t myk[4]; bool fa[4], fb[4];
    int asum = 0, bsum = 0;
    for (int k = 0; k < 4; ++k) {
        uint64_t key = kb[4 * tid + k]; myk[k] = key;
        unsigned hi = (unsigned)(key >> 32);
        fa[k] = (hi == 0x3F800000u);
        fb[k] = (__uint_as_float(hi) > CONF_T) && !fa[k];
        asum += fa[k] ? 1 : 0; bsum += fb[k] ? 1 : 0;
    }
    int ia = asum, ib = bsum;                       // wave-inclusive scans
    for (int off = 1; off < 64; off <<= 1) {
        int va = __shfl_up(ia, off), vb = __shfl_up(ib, off);
        if (lane >= off) { ia += va; ib += vb; }
    }
    if (lane == 63) { wsumA[wv] = ia; wsumB[wv] = ib; }
    __syncthreads();
    int baseA = 0, baseB = 0, cntA = 0, cntB = 0;
    for (int w2 = 0; w2 < 16; ++w2) {
        if (w2 < wv) { baseA += wsumA[w2]; baseB += wsumB[w2]; }
        cntA += wsumA[w2]; cntB += wsumB[w2];
    }
    int pA = baseA + (ia - asum);
    int pB = baseB + (ib - bsum);
    for (int k = 0; k < 4; ++k) {
        if (fa[k]) og[pA++] = 4 * tid + k;          // stable: idx order
        if (fb[k]) bbuf[pB++] = myk[k];             // pB < cntB <= 4096 always
    }
    __syncthreads();

    // ---- rank sort of B (descending, keys unique): one barrier ----
    for (int i = tid; i < cntB; i += 1024) {
        uint64_t ki = bbuf[i];
        int rank = 0;
        for (int j = 0; j < cntB; ++j) rank += (bbuf[j] > ki) ? 1 : 0;
        og[cntA + rank] = (int)(0xFFFFFFFFu - (unsigned)(ki & 0xFFFFFFFFull));
    }
    int nl = cntA + cntB; if (nl > NN) nl = NN;
    __syncthreads();   // bbuf reads done; og complete

    // ---- sorted corner build into LDS (overwrites bbuf region) ----
    for (int i = tid; i < nl; i += 1024) {
        int o = og[i];
        float4 bv = ((const float4*)bxp)[o];
        float y1 = fminf(bv.x, bv.z), y2 = fmaxf(bv.x, bv.z);
        float x1 = fminf(bv.y, bv.w), x2 = fmaxf(bv.y, bv.w);
        hy1[i] = y1; hx1[i] = x1; hy2[i] = y2; hx2[i] = x2;
        har[i] = (y2 - y1) * (x2 - x1);
    }
    if (tid == 0) { kept_s = 0; fk0_s = 0; done_s = 0; ccnt_s = 0; cur_s = 0; }

    // ---- rounds ----
    for (;;) {
        __syncthreads();                               // B1
        // -- refill clean list from raw [cursor, nl) --
        for (;;) {
            int cc0 = ccnt_s, cur = cur_s;
            if (cc0 >= TK || cur >= nl) break;         // uniform
            int i = cur + tid;
            bool v = i < nl;
            int f1 = kept_s;                           // < MAXD here (else done)
            if (f1 == 0) {                             // fast path: no keeps yet
                if (v) clist[cc0 + tid] = i;           // identity stable append
                if (tid == 0) {
                    int rem = nl - cur;
                    ccnt_s = cc0 + (rem < CH ? rem : CH);
                    cur_s = cur + CH;
                }
                __syncthreads();                       // writes visible
                continue;
            }
            int ii = v ? i : 0;
            float y1 = hy1[ii], x1 = hx1[ii], y2 = hy2[ii], x2 = hx2[ii], ar = har[ii];
            bool sup = false;
            for (int q = 0; q < f1; ++q) {             // wave-uniform broadcast reads
                float qy1 = ky1[q], qx1 = kx1[q], qy2 = ky2[q], qx2 = kx2[q], qar = kar[q];
                float ih = fmaxf(0.f, fminf(y2, qy2) - fmaxf(y1, qy1));
                float iw = fmaxf(0.f, fminf(x2, qx2) - fmaxf(x1, qx1));
                float inter = ih * iw;
                float uni = (ar + qar) - inter;
                sup = sup || (inter > 0.f && (double)inter > (double)uni * IOUC);
                if ((q & 15) == 15 && __ballot(v && !sup) == 0ull) break;
            }
            bool srv = v && !sup;
            int sflag = srv ? 1 : 0;
            int inc = sflag;
            for (int off = 1; off < 64; off <<= 1) {
                int v2 = __shfl_up(inc, off);
                if (lane >= off) inc += v2;
            }
            if (lane == 63) wsumC[wv] = inc;
            __syncthreads();                           // BA: scan ready
            int base = 0, tot = 0;
            for (int w2 = 0; w2 < 16; ++w2) {
                int s2 = wsumC[w2];
                if (w2 < wv) base += s2;
                tot += s2;
            }
            if (srv) clist[cc0 + base + (inc - sflag)] = i;   // stable append
            if (tid == 0) { ccnt_s = cc0 + tot; cur_s = cur + CH; }
            __syncthreads();                           // BB: writes visible
        }
        int cc = ccnt_s;
        int st = cc < TK ? cc : TK;
        // -- select + stage candidate corners --
        if (tid < TK) {
            int c = (tid < st) ? clist[tid] : -1;
            cand_s[tid] = c;
            int cx = c >= 0 ? c : 0;
            scy1[tid] = hy1[cx]; scx1[tid] = hx1[cx];
            scy2[tid] = hy2[cx]; scx2[tid] = hx2[cx];
            scar[tid] = har[cx];
        }
        __syncthreads();                               // B2
        if (st <= 0) break;

        // -- 256x256 kill matrix: lane caches 4 col boxes; 16 rows/wave --
        {
            float jy1[4], jx1[4], jy2[4], jx2[4], jar[4]; bool jv[4];
            #pragma unroll
            for (int w = 0; w < 4; ++w) {
                int j = 64 * w + lane;
                jv[w] = cand_s[j] >= 0;
                jy1[w] = scy1[j]; jx1[w] = scx1[j];
                jy2[w] = scy2[j]; jx2[w] = scx2[j]; jar[w] = scar[j];
            }
            #pragma unroll
            for (int r = 0; r < 16; ++r) {
                int t = wv * 16 + r;                   // wave-uniform row
                bool tv = cand_s[t] >= 0;
                float ty1 = scy1[t], tx1 = scx1[t], ty2 = scy2[t], tx2 = scx2[t], tar = scar[t];
                #pragma unroll
                for (int w = 0; w < 4; ++w) {
                    float ih = fmaxf(0.f, fminf(ty2, jy2[w]) - fmaxf(ty1, jy1[w]));
                    float iw = fmaxf(0.f, fminf(tx2, jx2[w]) - fmaxf(tx1, jx1[w]));
                    float inter = ih * iw;
                    float uni = (tar + jar[w]) - inter;
                    bool s = tv && jv[w] && (inter > 0.f) && ((double)inter > (double)uni * IOUC);
                    uint64_t bal = __ballot(s);
                    if (lane == 0) kill4[t][w] = bal;
                }
            }
        }
        __syncthreads();                               // B3
        // -- exact greedy replay over 4 words (wave0) + keep staging --
        if (wv == 0) {
            uint64_t s0 = 0, s1 = 0, s2 = 0, s3 = 0;
            uint64_t m0 = 0, m1 = 0, m2 = 0, m3 = 0;
            {
                int lim = st < 64 ? st : 64;
                for (int jj = 0; jj < lim; ++jj) {
                    uint64_t kk0 = kill4[jj][0], kk1 = kill4[jj][1];
                    uint64_t kk2 = kill4[jj][2], kk3 = kill4[jj][3];
                    if (!((s0 >> jj) & 1ull)) {
                        m0 |= 1ull << jj; s0 |= kk0; s1 |= kk1; s2 |= kk2; s3 |= kk3;
                    }
                }
            }
            if (st > 64) {
                int lim = st - 64; if (lim > 64) lim = 64;
                for (int jj = 0; jj < lim; ++jj) {
                    int j = 64 + jj;
                    uint64_t kk0 = kill4[j][0], kk1 = kill4[j][1];
                    uint64_t kk2 = kill4[j][2], kk3 = kill4[j][3];
                    if (!((s1 >> jj) & 1ull)) {
                        m1 |= 1ull << jj; s0 |= kk0; s1 |= kk1; s2 |= kk2; s3 |= kk3;
                    }
                }
            }
            if (st > 128) {
                int lim = st - 128; if (lim > 64) lim = 64;
                for (int jj = 0; jj < lim; ++jj) {
                    int j = 128 + jj;
                    uint64_t kk0 = kill4[j][0], kk1 = kill4[j][1];
                    uint64_t kk2 = kill4[j][2], kk3 = kill4[j][3];
                    if (!((s2 >> jj) & 1ull)) {
                        m2 |= 1ull << jj; s0 |= kk0; s1 |= kk1; s2 |= kk2; s3 |= kk3;
                    }
                }
            }
            if (st > 192) {
                int lim = st - 192; if (lim > 64) lim = 64;
                for (int jj = 0; jj < lim; ++jj) {
                    int j = 192 + jj;
                    uint64_t kk0 = kill4[j][0], kk1 = kill4[j][1];
                    uint64_t kk2 = kill4[j][2], kk3 = kill4[j][3];
                    if (!((s3 >> jj) & 1ull)) {
                        m3 |= 1ull << jj; s0 |= kk0; s1 |= kk1; s2 |= kk2; s3 |= kk3;
                    }
                }
            }
            int k0 = kept_s;
            int c0 = __popcll(m0), c1 = __popcll(m1), c2 = __popcll(m2), c3 = __popcll(m3);
            uint64_t below = (1ull << lane) - 1ull;
            if ((m0 >> lane) & 1ull) {
                int pos = k0 + __popcll(m0 & below);
                if (pos < MAXD) {
                    int j = lane;
                    kpos[pos] = cand_s[j];
                    ky1[pos] = scy1[j]; kx1[pos] = scx1[j];
                    ky2[pos] = scy2[j]; kx2[pos] = scx2[j]; kar[pos] = scar[j];
                }
            }
            if ((m1 >> lane) & 1ull) {
                int pos = k0 + c0 + __popcll(m1 & below);
                if (pos < MAXD) {
                    int j = 64 + lane;
                    kpos[pos] = cand_s[j];
                    ky1[pos] = scy1[j]; kx1[pos] = scx1[j];
                    ky2[pos] = scy2[j]; kx2[pos] = scx2[j]; kar[pos] = scar[j];
                }
            }
            if ((m2 >> lane) & 1ull) {
                int pos = k0 + c0 + c1 + __popcll(m2 & below);
                if (pos < MAXD) {
                    int j = 128 + lane;
                    kpos[pos] = cand_s[j];
                    ky1[pos] = scy1[j]; kx1[pos] = scx1[j];
                    ky2[pos] = scy2[j]; kx2[pos] = scx2[j]; kar[pos] = scar[j];
                }
            }
            if ((m3 >> lane) & 1ull) {
                int pos = k0 + c0 + c1 + c2 + __popcll(m3 & below);
                if (pos < MAXD) {
                    int j = 192 + lane;
                    kpos[pos] = cand_s[j];
                    ky1[pos] = scy1[j]; kx1[pos] = scx1[j];
                    ky2[pos] = scy2[j]; kx2[pos] = scx2[j]; kar[pos] = scar[j];
                }
            }
            if (lane == 0) {
                int k1 = k0 + c0 + c1 + c2 + c3;
                fk0_s = k0;
                kept_s = k1;
                // cc<TK => refill stopped because raw exhausted => all consumed
                done_s = (k1 >= MAXD || cc < TK) ? 1 : 0;
            }
        }
        __syncthreads();                               // B4
        if (done_s) break;

        // -- refilter C[st, cc) vs NEW keeps [f0, f1), compact to front --
        {
            int f0 = fk0_s, f1 = kept_s;               // f1 < MAXD (else done)
            int j = st + tid;                          // cc - st <= 1023: 1/thread
            bool v = j < cc;
            int idx = v ? clist[j] : 0;
            float y1 = hy1[idx], x1 = hx1[idx], y2 = hy2[idx], x2 = hx2[idx], ar = har[idx];
            bool sup = false;
            for (int q = f0; q < f1; ++q) {            // wave-uniform broadcast reads
                float qy1 = ky1[q], qx1 = kx1[q], qy2 = ky2[q], qx2 = kx2[q], qar = kar[q];
                float ih = fmaxf(0.f, fminf(y2, qy2) - fmaxf(y1, qy1));
                float iw = fmaxf(0.f, fminf(x2, qx2) - fmaxf(x1, qx1));
                float inter = ih * iw;
                float uni = (ar + qar) - inter;
                sup = sup || (inter > 0.f && (double)inter > (double)uni * IOUC);
                if (((q - f0) & 15) == 15 && __ballot(v && !sup) == 0ull) break;
            }
            bool srv = v && !sup;
            int sflag = srv ? 1 : 0;
            int inc = sflag;
            for (int off = 1; off < 64; off <<= 1) {
                int v2 = __shfl_up(inc, off);
                if (lane >= off) inc += v2;
            }
            if (lane == 63) wsumC[wv] = inc;
            __syncthreads();                           // B5: all clist reads done
            int base = 0, tot = 0;
            for (int w2 = 0; w2 < 16; ++w2) {
                int s2 = wsumC[w2];
                if (w2 < wv) base += s2;
                tot += s2;
            }
            if (srv) clist[base + (inc - sflag)] = idx;  // stable left-compact
            if (tid == 0) ccnt_s = tot;
            // next round's B1 publishes
        }
    }

    // ---- fused output gather (exact k_gather semantics) ----
    int kt = kept_s; if (kt > MAXD) kt = MAXD;
    if (tid < MAXD) clist[tid] = (tid < kt) ? og[kpos[tid]] : 0;
    __syncthreads();

    float* ob = out_box + (size_t)b * MAXD * 4;
    float* oc = out_cls + (size_t)b * MAXD * CC;
    const float* pb = probs + (size_t)b * NN * CC;
    for (int r = tid; r < MAXD * 4; r += 1024) {
        int t = r >> 2, e2 = r & 3;
        float val = 0.0f;
        if (t < kt) { int idx = clist[t]; val = bxp[(size_t)idx * 4 + e2]; }
        ob[r] = val;
    }
    for (int q = tid; q < MAXD * CC; q += 1024) {
        int t = q / CC, c = q - t * CC;
        float val = 0.0f;
        if (t < kt) { int idx = clist[t]; val = pb[(size_t)idx * CC + c]; }
        oc[q] = val;
    }
}

// ---------------------------------------------------------------------------
// K4: wide parallel gather (fallback path only).
// ---------------------------------------------------------------------------
__global__ __launch_bounds__(256) void k_gather(const float* __restrict__ boxes,
                                                const float* __restrict__ probs,
                                                const int* __restrict__ kidx,
                                                const int* __restrict__ cnt,
                                                float* __restrict__ out_box,
                                                float* __restrict__ out_cls) {
    int u = blockIdx.x * 256 + threadIdx.x;
    if (u >= BB * PER_B) return;
    int b = u / PER_B;
    int r = u - b * PER_B;
    int count = cnt[b];
    float val = 0.0f;
    if (r < MAXD * 4) {
        int t = r >> 2, e = r & 3;
        if (t < count) {
            int idx = kidx[b * MAXD + t];
            val = boxes[((size_t)b * NN + idx) * 4 + e];
        }
        out_box[(size_t)b * MAXD * 4 + r] = val;
    } else {
        int q = r - MAXD * 4;
        int t = q / CC, c = q - t * CC;
        if (t < count) {
            int idx = kidx[b * MAXD + t];
            val = probs[((size_t)b * NN + idx) * CC + c];
        }
        out_cls[(size_t)b * MAXD * CC + q] = val;
    }
}

// ---------------------------------------------------------------------------
// FALLBACK (ws too small): round-4 fused k_nms — verified passing.
// ---------------------------------------------------------------------------
__global__ __launch_bounds__(1024) void k_nms_fb(uint64_t* keys,
                                                 const float* __restrict__ boxes,
                                                 int* __restrict__ kidx_out,
                                                 int* __restrict__ cnt_out) {
#pragma clang fp contract(off)
    __shared__ float sy1[SEGSZ], sx1[SEGSZ], sy2[SEGSZ], sx2[SEGSZ];
    __shared__ int   soidx[SEGSZ];
    __shared__ uint64_t bbuf[FBCAP];
    __shared__ uint64_t sup[NWORDS];
    __shared__ float ky1[MAXD], kx1[MAXD], ky2[MAXD], kx2[MAXD], kar[MAXD];
    __shared__ int   keptidx[MAXD];
    __shared__ int   wsumA[16], wsumB[16];
    __shared__ int   keptcnt_s, ctrl_s, seg_s;

    const int tid = threadIdx.x, lane = tid & 63, wv = tid >> 6;
    const int b = blockIdx.x;
    const uint64_t* kb = keys + (size_t)b * NN;
    const float* bxp = boxes + (size_t)b * NN * 4;
    int* og = (int*)(keys + (size_t)b * NN);

    uint64_t myk[4]; bool fa[4], fb[4];
    int asum = 0, bsum = 0;
    for (int k = 0; k < 4; ++k) {
        uint64_t key = kb[4 * tid + k]; myk[k] = key;
        unsigned hi = (unsigned)(key >> 32);
        fa[k] = (hi == 0x3F800000u);
        fb[k] = (__uint_as_float(hi) > CONF_T) && !fa[k];
        asum += fa[k] ? 1 : 0; bsum += fb[k] ? 1 : 0;
    }
    int ia = asum, ib = bsum;
    for (int off = 1; off < 64; off <<= 1) {
        int va = __shfl_up(ia, off), vb = __shfl_up(ib, off);
        if (lane >= off) { ia += va; ib += vb; }
    }
    if (lane == 63) { wsumA[wv] = ia; wsumB[wv] = ib; }
    __syncthreads();
    int baseA = 0, baseB = 0, cntA = 0, cntB = 0;
    for (int w2 = 0; w2 < 16; ++w2) {
        if (w2 < wv) { baseA += wsumA[w2]; baseB += wsumB[w2]; }
        cntA += wsumA[w2]; cntB += wsumB[w2];
    }
    int pA = baseA + (ia - asum);
    int pB = baseB + (ib - bsum);
    for (int k = 0; k < 4; ++k) {
        if (fa[k]) og[pA++] = 4 * tid + k;
        if (fb[k]) { if (pB < FBCAP) bbuf[pB] = myk[k]; pB++; }
    }
    int cntBc = cntB < FBCAP ? cntB : FBCAP;
    int nlist = cntA + cntBc;
    if (tid == 0) { keptcnt_s = 0; seg_s = 0; }
    for (int i = tid; i < FBCAP; i += 1024) if (i >= cntB) bbuf[i] = 0;
    __syncthreads();

    for (unsigned k2 = 2; k2 <= FBCAP; k2 <<= 1) {
        for (unsigned j = k2 >> 1; j > 0; j >>= 1) {
            for (unsigned i = tid; i < FBCAP; i += 1024) {
                unsigned p = i ^ j;
                if (p > i) {
                    uint64_t va = bbuf[i], vb = bbuf[p];
                    bool desc = ((i & k2) == 0);
                    if (desc ? (va < vb) : (va > vb)) { bbuf[i] = vb; bbuf[p] = va; }
                }
            }
            __syncthreads();
        }
    }
    for (int i = tid; i < cntBc; i += 1024)
        og[cntA + i] = (int)(0xFFFFFFFFu - (unsigned)(bbuf[i] & 0xFFFFFFFFull));
    if (tid < NWORDS) {
        int lo = tid * 64;
        uint64_t mm;
        if (nlist <= lo) mm = ~0ull;
        else if (nlist >= lo + 64) mm = 0ull;
        else mm = (~0ull) << (nlist - lo);
        sup[tid] = mm;
    }
    __syncthreads();

    for (int i = tid; i < SEGSZ; i += 1024) {
        if (i < nlist) {
            int o = og[i];
            soidx[i] = o;
            const float* bp = bxp + (size_t)o * 4;
            float b0 = bp[0], b1 = bp[1], b2 = bp[2], b3 = bp[3];
            sy1[i] = fminf(b0, b2); sy2[i] = fmaxf(b0, b2);
            sx1[i] = fminf(b1, b3); sx2[i] = fmaxf(b1, b3);
        }
    }
    __syncthreads();

    int curw = 0, segr = 0;
    while (true) {
        if (tid == 0) {
            int code = -1;
            for (;;) {
                int wend = (segr + 1) * (SEGSZ / 64);
                if (curw >= wend) {
                    if (segr == 0 && nlist > SEGSZ) {
                        code = -2; segr = 1; seg_s = 1; curw = SEGSZ / 64;
                    } else code = -1;
                    break;
                }
                uint64_t live = ~sup[curw];
                if (live) {
                    int j = __ffsll((unsigned long long)live) - 1;
                    int sel = curw * 64 + j;
                    int li = sel - segr * SEGSZ;
                    int kc = keptcnt_s;
                    keptidx[kc] = soidx[li];
                    ky1[kc] = sy1[li]; kx1[kc] = sx1[li];
                    ky2[kc] = sy2[li]; kx2[kc] = sx2[li];
                    kar[kc] = (sy2[li] - sy1[li]) * (sx2[li] - sx1[li]);
                    keptcnt_s = kc + 1;
                    sup[curw] |= (1ull << j);
                    code = (kc + 1 >= MAXD) ? -1 : sel;
                    break;
                }
                ++curw;
            }
            ctrl_s = code;
        }
        __syncthreads();
        int c = ctrl_s;
        if (c == -1) break;

        if (c == -2) {
            for (int i = tid; i < SEGSZ; i += 1024) {
                int gi = SEGSZ + i;
                if (gi < nlist) {
                    int o = og[gi];
                    soidx[i] = o;
                    const float* bp = bxp + (size_t)o * 4;
                    float b0 = bp[0], b1 = bp[1], b2 = bp[2], b3 = bp[3];
                    sy1[i] = fminf(b0, b2); sy2[i] = fmaxf(b0, b2);
                    sx1[i] = fminf(b1, b3); sx2[i] = fmaxf(b1, b3);
                }
            }
            __syncthreads();
            int kc = keptcnt_s;
            for (int k = 0; k < 2; ++k) {
                int li = tid + k * 1024;
                float y1 = sy1[li], y2 = sy2[li], x1 = sx1[li], x2 = sx2[li];
                float ar = (y2 - y1) * (x2 - x1);
                bool s = false;
                for (int q = 0; q < kc; ++q) {
                    float ih = fmaxf(0.f, fminf(y2, ky2[q]) - fmaxf(y1, ky1[q]));
                    float iw = fmaxf(0.f, fminf(x2, kx2[q]) - fmaxf(x1, kx1[q]));
                    float inter = ih * iw;
                    float uni = (ar + kar[q]) - inter;
                    s = s || (inter > 0.f && inter / uni > 0.5f);
                }
                uint64_t bal = __ballot(s);
                if (lane == 0 && bal) {
                    int word = (SEGSZ + k * 1024 + wv * 64) >> 6;
                    sup[word] |= bal;
                }
            }
            __syncthreads();
            continue;
        }

        int sg = seg_s;
        int cl = c - sg * SEGSZ;
        float cy1 = sy1[cl], cy2 = sy2[cl], cx1 = sx1[cl], cx2 = sx2[cl];
        float car = (cy2 - cy1) * (cx2 - cx1);
        for (int k = 0; k < 2; ++k) {
            int li = tid + k * 1024;
            float y1 = sy1[li], y2 = sy2[li], x1 = sx1[li], x2 = sx2[li];
            float ar = (y2 - y1) * (x2 - x1);
            float ih = fmaxf(0.f, fminf(y2, cy2) - fmaxf(y1, cy1));
            float iw = fmaxf(0.f, fminf(x2, cx2) - fmaxf(x1, cx1));
            float inter = ih * iw;
            float uni = (ar + car) - inter;
            bool s = (inter > 0.f) && (inter / uni > 0.5f);
            uint64_t bal = __ballot(s);
            if (lane == 0 && bal) {
                int word = (sg * SEGSZ + k * 1024 + wv * 64) >> 6;
                sup[word] |= bal;
            }
        }
        __syncthreads();
    }

    if (tid == 0) cnt_out[b] = keptcnt_s;
    for (int i = tid; i < MAXD; i += 1024)
        kidx_out[b * MAXD + i] = (i < keptcnt_s) ? keptidx[i] : 0;
}

extern "C" void kernel_launch(void* const* d_in, const int* in_sizes, int n_in,
                              void* d_out, int out_size, void* d_ws, size_t ws_size,
                              hipStream_t stream) {
    const float* boxes = (const float*)d_in[0];   // [B,N,4]
    const float* cls   = (const float*)d_in[1];   // [B,N,C]
    float* out = (float*)d_out;
    float* out_box = out;                                                  // [B,100,4]
    float* out_cls = out + (size_t)BB * MAXD * 4;                          // [B,100,80]
    float* probs   = out + (size_t)BB * MAXD * 4 + (size_t)BB * MAXD * CC; // [B,N,80]

    char* ws = (char*)d_ws;
    uint64_t* keys = (uint64_t*)(ws + WS_KEYS);

    k_softmax<<<(BB * NN * 8) / 256, 256, 0, stream>>>(cls, probs, keys);

    if (ws_size >= (size_t)WS_NEED) {
        k_pnms<<<BB, 1024, 0, stream>>>(keys, boxes, probs, out_box, out_cls);
    } else {
        int* kidx = (int*)(ws + (size_t)BB * NN * sizeof(uint64_t));
        int* cnt  = kidx + BB * MAXD;
        k_nms_fb<<<BB, 1024, 0, stream>>>(keys, boxes, kidx, cnt);
        k_gather<<<(BB * PER_B + 255) / 256, 256, 0, stream>>>(boxes, probs, kidx, cnt,
                                                               out_box, out_cls);
    }
}

// Round 4
// 100.884 us; speedup vs baseline: 1.1564x; 1.1564x over previous
//
#include <hip/hip_runtime.h>
#include <cstdint>
#include <cstddef>

#define BB 16
#define NN 4096
#define CC 80
#define MAXD 100
#define CONF_T 0.5f
#define PER_B (MAXD * 4 + MAXD * CC)   // 8400 output elems per batch
#define NWORDS 64                      // 4096/64 bitmap words (fallback)
#define FBCAP 2048                     // fallback kernel's capacity
#define SEGSZ 2048

// fl32(inter/uni) > 0.5  <=>  inter > uni*(0.5+2^-25), evaluated EXACTLY in
// fp64 (24-bit x 25-bit mantissa product = 49 bits < 53). Bit-identical to
// the reference's IEEE divide + compare. (verified passing rounds 9)
#define IOUC 0x1.000001p-1

// ---- workspace layout ----
#define WS_KEYS   0x000000             // [B*N] u64
#define WS_NEED   0x200000             // 2 MB

// ---------------------------------------------------------------------------
// K1: softmax of (10x)^2 per row — 8 LANES per row, all-register, no LDS.
// Lane j owns elements {j, j+8, ..., j+72}: exactly the numpy pairwise-8
// groups, so the sequential per-lane accumulation == r8[j] chain bitwise.
// Cross-lane max: fmaxf commutative/associative over finite z>=0. Cross-lane
// sum: shfl_xor tree == ((r0+r1)+(r2+r3))+((r4+r5)+(r6+r7)) bitwise.
// (verified passing round 2)
// ---------------------------------------------------------------------------
__global__ __launch_bounds__(256) void k_softmax(const float* __restrict__ cls_in,
                                                 float* __restrict__ probs,
                                                 uint64_t* __restrict__ keys) {
#pragma clang fp contract(off)
    int slot = blockIdx.x * 256 + threadIdx.x;   // 8 slots per row
    int row  = slot >> 3;                        // [0, B*N)
    int j    = slot & 7;
    const float* rp = cls_in + (size_t)row * CC + j;

    float e[10];
    float m = -3.402823466e+38f;
    #pragma unroll
    for (int k = 0; k < 10; ++k) {
        float y = rp[8 * k] * 10.0f;
        float z = y * y;
        e[k] = z;
        m = fmaxf(m, z);
    }
    m = fmaxf(m, __shfl_xor(m, 1));
    m = fmaxf(m, __shfl_xor(m, 2));
    m = fmaxf(m, __shfl_xor(m, 4));

    #pragma unroll
    for (int k = 0; k < 10; ++k) e[k] = expf(e[k] - m);

    float acc = e[0];
    #pragma unroll
    for (int k = 1; k < 10; ++k) acc += e[k];    // r8[j] sequential chain
    acc = acc + __shfl_xor(acc, 1);              // (r0+r1) ...
    acc = acc + __shfl_xor(acc, 2);              // (r0+r1)+(r2+r3) ...
    acc = acc + __shfl_xor(acc, 4);              // full pairwise tree

    float score = 1.0f / acc;
    float* pp = probs + (size_t)row * CC + j;
    #pragma unroll
    for (int k = 0; k < 10; ++k) pp[8 * k] = e[k] * score;

    if (j == 0) {
        unsigned n = (unsigned)(row & (NN - 1));
        keys[row] = ((uint64_t)__float_as_uint(score) << 32)
                  | (uint64_t)(0xFFFFFFFFu - n);
    }
}

// ---------------------------------------------------------------------------
// K2 (fused): partition + rank-sort + LDS corner build + BLOCK-SEQUENTIAL NMS
//             + fused output gather. One block (1024 thr = 16 waves)/batch.
//
// No clean list. Candidates processed in raw sorted order, 64 per g-block:
//   phase1 (all waves): pre-filter block's 64 cands vs keeps-so-far, with the
//     keep range STRIDED ACROSS the 16 waves (~7 keeps/wave, LDS broadcast
//     reads); per-wave ballot -> persup[wv]; OR-fold = sup_init.
//     Each candidate is checked vs each keep exactly once, ever.
//   phase2 (all waves): 64x64 kill matrix, 4 row-ballots per wave (verbatim).
//   phase3 (wave0): exact greedy replay from sup_init, 8x8 register-prefetch
//     of kill words (loads independent of the serial bit-test chain);
//     append keeps in ascending position; stage kept corners for phase1.
//   all-dead blocks (sup_init == ~0) skip phases 2-3 uniformly.
// done <=> kept>=100 or blocks exhausted. Identical greedy result to the
// reference: ascending-position processing, pre-suppression = kills by
// earlier keeps, in-block replay ascending, exact IoU compare throughout.
// ---------------------------------------------------------------------------
__global__ __launch_bounds__(1024) void k_pnms(const uint64_t* __restrict__ keys,
                                               const float* __restrict__ boxes,
                                               const float* __restrict__ probs,
                                               float* __restrict__ out_box,
                                               float* __restrict__ out_cls) {
#pragma clang fp contract(off)
    __shared__ __align__(16) unsigned char sraw[6 * NN * 4];   // 96 KB
    float* hy1 = (float*)sraw;
    float* hx1 = (float*)(sraw + NN * 4);
    float* hy2 = (float*)(sraw + 2 * NN * 4);
    float* hx2 = (float*)(sraw + 3 * NN * 4);
    float* har = (float*)(sraw + 4 * NN * 4);
    int*   og  = (int*)(sraw + 5 * NN * 4);
    uint64_t* bbuf = (uint64_t*)sraw;          // overlays hy1+hx1 (32 KB); dead after sort
    __shared__ uint64_t kill[64];
    __shared__ uint64_t persup[16];
    __shared__ float ky1[MAXD], kx1[MAXD], ky2[MAXD], kx2[MAXD], kar[MAXD]; // staged keeps
    __shared__ int kpos[MAXD];
    __shared__ int fidx[MAXD];
    __shared__ int wsumA[16], wsumB[16];
    __shared__ int kept_s, done_s;

    const int tid = threadIdx.x, lane = tid & 63, wv = tid >> 6;
    const int b = blockIdx.x;
    const uint64_t* kb = keys + (size_t)b * NN;
    const float* bxp = boxes + (size_t)b * NN * 4;

    // ---- partition (og/bbuf in LDS, keys untouched) ----
    uint64_t myk[4]; bool fa[4], fb[4];
    int asum = 0, bsum = 0;
    for (int k = 0; k < 4; ++k) {
        uint64_t key = kb[4 * tid + k]; myk[k] = key;
        unsigned hi = (unsigned)(key >> 32);
        fa[k] = (hi == 0x3F800000u);
        fb[k] = (__uint_as_float(hi) > CONF_T) && !fa[k];
        asum += fa[k] ? 1 : 0; bsum += fb[k] ? 1 : 0;
    }
    int ia = asum, ib = bsum;                       // wave-inclusive scans
    for (int off = 1; off < 64; off <<= 1) {
        int va = __shfl_up(ia, off), vb = __shfl_up(ib, off);
        if (lane >= off) { ia += va; ib += vb; }
    }
    if (lane == 63) { wsumA[wv] = ia; wsumB[wv] = ib; }
    __syncthreads();
    int baseA = 0, baseB = 0, cntA = 0, cntB = 0;
    for (int w2 = 0; w2 < 16; ++w2) {
        if (w2 < wv) { baseA += wsumA[w2]; baseB += wsumB[w2]; }
        cntA += wsumA[w2]; cntB += wsumB[w2];
    }
    int pA = baseA + (ia - asum);
    int pB = baseB + (ib - bsum);
    for (int k = 0; k < 4; ++k) {
        if (fa[k]) og[pA++] = 4 * tid + k;          // stable: idx order
        if (fb[k]) bbuf[pB++] = myk[k];             // pB < cntB <= 4096 always
    }
    __syncthreads();

    // ---- rank sort of B (descending, keys unique): one barrier ----
    for (int i = tid; i < cntB; i += 1024) {
        uint64_t ki = bbuf[i];
        int rank = 0;
        for (int j = 0; j < cntB; ++j) rank += (bbuf[j] > ki) ? 1 : 0;
        og[cntA + rank] = (int)(0xFFFFFFFFu - (unsigned)(ki & 0xFFFFFFFFull));
    }
    int nl = cntA + cntB; if (nl > NN) nl = NN;
    __syncthreads();   // bbuf reads done; og complete

    // ---- sorted corner build into LDS (overwrites bbuf region) ----
    for (int i = tid; i < nl; i += 1024) {
        int o = og[i];
        float4 bv = ((const float4*)bxp)[o];
        float y1 = fminf(bv.x, bv.z), y2 = fmaxf(bv.x, bv.z);
        float x1 = fminf(bv.y, bv.w), x2 = fmaxf(bv.y, bv.w);
        hy1[i] = y1; hx1[i] = x1; hy2[i] = y2; hx2[i] = x2;
        har[i] = (y2 - y1) * (x2 - x1);
    }
    if (tid == 0) { kept_s = 0; done_s = 0; }

    // ---- block-sequential greedy over 64-wide g-blocks ----
    int ng = (nl + 63) >> 6;
    for (int g = 0; g < ng; ++g) {
        __syncthreads();                           // S0: publish kept/done/persup reuse
        if (done_s) break;                         // uniform
        int kt = kept_s;                           // uniform; < MAXD here (else done)
        int i = g * 64 + lane;
        bool v = i < nl;
        int ii = v ? i : 0;
        float y1 = hy1[ii], x1 = hx1[ii], y2 = hy2[ii], x2 = hx2[ii], ar = har[ii];

        // -- phase 1: pre-filter vs keeps, strided across waves --
        bool killed = false;
        for (int q = wv; q < kt; q += 16) {        // wave-uniform broadcast reads
            float qy1 = ky1[q], qx1 = kx1[q], qy2 = ky2[q], qx2 = kx2[q], qar = kar[q];
            float ih = fmaxf(0.f, fminf(y2, qy2) - fmaxf(y1, qy1));
            float iw = fmaxf(0.f, fminf(x2, qx2) - fmaxf(x1, qx1));
            float inter = ih * iw;
            float uni = (ar + qar) - inter;
            killed = killed || (inter > 0.f && (double)inter > (double)uni * IOUC);
        }
        uint64_t pw = __ballot((!v) || killed);
        if (lane == 0) persup[wv] = pw;
        __syncthreads();                           // S1: persup ready
        uint64_t sup0 = 0;
        #pragma unroll
        for (int w2 = 0; w2 < 16; ++w2) sup0 |= persup[w2];
        if (sup0 == ~0ull) continue;               // uniform: block fully dead

        // -- phase 2: 64x64 kill matrix, 4 row-ballots per wave --
        #pragma unroll
        for (int r = 0; r < 4; ++r) {
            int t = wv + 16 * r;
            int it = g * 64 + t;
            bool tv = it < nl;
            int itx = tv ? it : 0;
            float ty1 = hy1[itx], tx1 = hx1[itx], ty2 = hy2[itx], tx2 = hx2[itx], tar = har[itx];
            float ih = fmaxf(0.f, fminf(ty2, y2) - fmaxf(ty1, y1));
            float iw = fmaxf(0.f, fminf(tx2, x2) - fmaxf(tx1, x1));
            float inter = ih * iw;
            float uni = (tar + ar) - inter;
            bool s = tv && v && (inter > 0.f) && ((double)inter > (double)uni * IOUC);
            uint64_t w = __ballot(s);
            if (lane == 0) kill[t] = w;
        }
        __syncthreads();                           // S2: kill ready

        // -- phase 3: exact greedy replay (wave0), 8x8 register prefetch --
        if (wv == 0) {
            uint64_t sup = sup0, keptm = 0;
            #pragma unroll
            for (int c8 = 0; c8 < 8; ++c8) {
                uint64_t kk[8];
                #pragma unroll
                for (int u = 0; u < 8; ++u) kk[u] = kill[c8 * 8 + u];  // independent loads
                #pragma unroll
                for (int u = 0; u < 8; ++u) {
                    int t = c8 * 8 + u;
                    if (!((sup >> t) & 1ull)) { keptm |= 1ull << t; sup |= kk[u]; }
                }
            }
            int k0 = kept_s;
            if ((keptm >> lane) & 1ull) {
                int pos = k0 + __popcll(keptm & ((1ull << lane) - 1ull));
                if (pos < MAXD) {
                    kpos[pos] = i;
                    ky1[pos] = y1; kx1[pos] = x1;
                    ky2[pos] = y2; kx2[pos] = x2; kar[pos] = ar;
                }
            }
            if (lane == 0) {
                int k1 = k0 + __popcll(keptm);
                kept_s = k1;
                done_s = (k1 >= MAXD) ? 1 : 0;
            }
        }
        // next iteration's S0 (or the final barrier) publishes wave0's writes
    }
    __syncthreads();                               // publish kept_s/kpos (g==ng exit path)

    // ---- fused output gather (exact k_gather semantics) ----
    int kt = kept_s; if (kt > MAXD) kt = MAXD;
    if (tid < MAXD) fidx[tid] = (tid < kt) ? og[kpos[tid]] : 0;
    __syncthreads();

    float* ob = out_box + (size_t)b * MAXD * 4;
    float* oc = out_cls + (size_t)b * MAXD * CC;
    const float* pb = probs + (size_t)b * NN * CC;
    for (int r = tid; r < MAXD * 4; r += 1024) {
        int t = r >> 2, e2 = r & 3;
        float val = 0.0f;
        if (t < kt) { int idx = fidx[t]; val = bxp[(size_t)idx * 4 + e2]; }
        ob[r] = val;
    }
    for (int q = tid; q < MAXD * CC; q += 1024) {
        int t = q / CC, c = q - t * CC;
        float val = 0.0f;
        if (t < kt) { int idx = fidx[t]; val = pb[(size_t)idx * CC + c]; }
        oc[q] = val;
    }
}

// ---------------------------------------------------------------------------
// K4: wide parallel gather (fallback path only).
// ---------------------------------------------------------------------------
__global__ __launch_bounds__(256) void k_gather(const float* __restrict__ boxes,
                                                const float* __restrict__ probs,
                                                const int* __restrict__ kidx,
                                                const int* __restrict__ cnt,
                                                float* __restrict__ out_box,
                                                float* __restrict__ out_cls) {
    int u = blockIdx.x * 256 + threadIdx.x;
    if (u >= BB * PER_B) return;
    int b = u / PER_B;
    int r = u - b * PER_B;
    int count = cnt[b];
    float val = 0.0f;
    if (r < MAXD * 4) {
        int t = r >> 2, e = r & 3;
        if (t < count) {
            int idx = kidx[b * MAXD + t];
            val = boxes[((size_t)b * NN + idx) * 4 + e];
        }
        out_box[(size_t)b * MAXD * 4 + r] = val;
    } else {
        int q = r - MAXD * 4;
        int t = q / CC, c = q - t * CC;
        if (t < count) {
            int idx = kidx[b * MAXD + t];
            val = probs[((size_t)b * NN + idx) * CC + c];
        }
        out_cls[(size_t)b * MAXD * CC + q] = val;
    }
}

// ---------------------------------------------------------------------------
// FALLBACK (ws too small): round-4 fused k_nms — verified passing.
// ---------------------------------------------------------------------------
__global__ __launch_bounds__(1024) void k_nms_fb(uint64_t* keys,
                                                 const float* __restrict__ boxes,
                                                 int* __restrict__ kidx_out,
                                                 int* __restrict__ cnt_out) {
#pragma clang fp contract(off)
    __shared__ float sy1[SEGSZ], sx1[SEGSZ], sy2[SEGSZ], sx2[SEGSZ];
    __shared__ int   soidx[SEGSZ];
    __shared__ uint64_t bbuf[FBCAP];
    __shared__ uint64_t sup[NWORDS];
    __shared__ float ky1[MAXD], kx1[MAXD], ky2[MAXD], kx2[MAXD], kar[MAXD];
    __shared__ int   keptidx[MAXD];
    __shared__ int   wsumA[16], wsumB[16];
    __shared__ int   keptcnt_s, ctrl_s, seg_s;

    const int tid = threadIdx.x, lane = tid & 63, wv = tid >> 6;
    const int b = blockIdx.x;
    const uint64_t* kb = keys + (size_t)b * NN;
    const float* bxp = boxes + (size_t)b * NN * 4;
    int* og = (int*)(keys + (size_t)b * NN);

    uint64_t myk[4]; bool fa[4], fb[4];
    int asum = 0, bsum = 0;
    for (int k = 0; k < 4; ++k) {
        uint64_t key = kb[4 * tid + k]; myk[k] = key;
        unsigned hi = (unsigned)(key >> 32);
        fa[k] = (hi == 0x3F800000u);
        fb[k] = (__uint_as_float(hi) > CONF_T) && !fa[k];
        asum += fa[k] ? 1 : 0; bsum += fb[k] ? 1 : 0;
    }
    int ia = asum, ib = bsum;
    for (int off = 1; off < 64; off <<= 1) {
        int va = __shfl_up(ia, off), vb = __shfl_up(ib, off);
        if (lane >= off) { ia += va; ib += vb; }
    }
    if (lane == 63) { wsumA[wv] = ia; wsumB[wv] = ib; }
    __syncthreads();
    int baseA = 0, baseB = 0, cntA = 0, cntB = 0;
    for (int w2 = 0; w2 < 16; ++w2) {
        if (w2 < wv) { baseA += wsumA[w2]; baseB += wsumB[w2]; }
        cntA += wsumA[w2]; cntB += wsumB[w2];
    }
    int pA = baseA + (ia - asum);
    int pB = baseB + (ib - bsum);
    for (int k = 0; k < 4; ++k) {
        if (fa[k]) og[pA++] = 4 * tid + k;
        if (fb[k]) { if (pB < FBCAP) bbuf[pB] = myk[k]; pB++; }
    }
    int cntBc = cntB < FBCAP ? cntB : FBCAP;
    int nlist = cntA + cntBc;
    if (tid == 0) { keptcnt_s = 0; seg_s = 0; }
    for (int i = tid; i < FBCAP; i += 1024) if (i >= cntB) bbuf[i] = 0;
    __syncthreads();

    for (unsigned k2 = 2; k2 <= FBCAP; k2 <<= 1) {
        for (unsigned j = k2 >> 1; j > 0; j >>= 1) {
            for (unsigned i = tid; i < FBCAP; i += 1024) {
                unsigned p = i ^ j;
                if (p > i) {
                    uint64_t va = bbuf[i], vb = bbuf[p];
                    bool desc = ((i & k2) == 0);
                    if (desc ? (va < vb) : (va > vb)) { bbuf[i] = vb; bbuf[p] = va; }
                }
            }
            __syncthreads();
        }
    }
    for (int i = tid; i < cntBc; i += 1024)
        og[cntA + i] = (int)(0xFFFFFFFFu - (unsigned)(bbuf[i] & 0xFFFFFFFFull));
    if (tid < NWORDS) {
        int lo = tid * 64;
        uint64_t mm;
        if (nlist <= lo) mm = ~0ull;
        else if (nlist >= lo + 64) mm = 0ull;
        else mm = (~0ull) << (nlist - lo);
        sup[tid] = mm;
    }
    __syncthreads();

    for (int i = tid; i < SEGSZ; i += 1024) {
        if (i < nlist) {
            int o = og[i];
            soidx[i] = o;
            const float* bp = bxp + (size_t)o * 4;
            float b0 = bp[0], b1 = bp[1], b2 = bp[2], b3 = bp[3];
            sy1[i] = fminf(b0, b2); sy2[i] = fmaxf(b0, b2);
            sx1[i] = fminf(b1, b3); sx2[i] = fmaxf(b1, b3);
        }
    }
    __syncthreads();

    int curw = 0, segr = 0;
    while (true) {
        if (tid == 0) {
            int code = -1;
            for (;;) {
                int wend = (segr + 1) * (SEGSZ / 64);
                if (curw >= wend) {
                    if (segr == 0 && nlist > SEGSZ) {
                        code = -2; segr = 1; seg_s = 1; curw = SEGSZ / 64;
                    } else code = -1;
                    break;
                }
                uint64_t live = ~sup[curw];
                if (live) {
                    int j = __ffsll((unsigned long long)live) - 1;
                    int sel = curw * 64 + j;
                    int li = sel - segr * SEGSZ;
                    int kc = keptcnt_s;
                    keptidx[kc] = soidx[li];
                    ky1[kc] = sy1[li]; kx1[kc] = sx1[li];
                    ky2[kc] = sy2[li]; kx2[kc] = sx2[li];
                    kar[kc] = (sy2[li] - sy1[li]) * (sx2[li] - sx1[li]);
                    keptcnt_s = kc + 1;
                    sup[curw] |= (1ull << j);
                    code = (kc + 1 >= MAXD) ? -1 : sel;
                    break;
                }
                ++curw;
            }
            ctrl_s = code;
        }
        __syncthreads();
        int c = ctrl_s;
        if (c == -1) break;

        if (c == -2) {
            for (int i = tid; i < SEGSZ; i += 1024) {
                int gi = SEGSZ + i;
                if (gi < nlist) {
                    int o = og[gi];
                    soidx[i] = o;
                    const float* bp = bxp + (size_t)o * 4;
                    float b0 = bp[0], b1 = bp[1], b2 = bp[2], b3 = bp[3];
                    sy1[i] = fminf(b0, b2); sy2[i] = fmaxf(b0, b2);
                    sx1[i] = fminf(b1, b3); sx2[i] = fmaxf(b1, b3);
                }
            }
            __syncthreads();
            int kc = keptcnt_s;
            for (int k = 0; k < 2; ++k) {
                int li = tid + k * 1024;
                float y1 = sy1[li], y2 = sy2[li], x1 = sx1[li], x2 = sx2[li];
                float ar = (y2 - y1) * (x2 - x1);
                bool s = false;
                for (int q = 0; q < kc; ++q) {
                    float ih = fmaxf(0.f, fminf(y2, ky2[q]) - fmaxf(y1, ky1[q]));
                    float iw = fmaxf(0.f, fminf(x2, kx2[q]) - fmaxf(x1, kx1[q]));
                    float inter = ih * iw;
                    float uni = (ar + kar[q]) - inter;
                    s = s || (inter > 0.f && inter / uni > 0.5f);
                }
                uint64_t bal = __ballot(s);
                if (lane == 0 && bal) {
                    int word = (SEGSZ + k * 1024 + wv * 64) >> 6;
                    sup[word] |= bal;
                }
            }
            __syncthreads();
            continue;
        }

        int sg = seg_s;
        int cl = c - sg * SEGSZ;
        float cy1 = sy1[cl], cy2 = sy2[cl], cx1 = sx1[cl], cx2 = sx2[cl];
        float car = (cy2 - cy1) * (cx2 - cx1);
        for (int k = 0; k < 2; ++k) {
            int li = tid + k * 1024;
            float y1 = sy1[li], y2 = sy2[li], x1 = sx1[li], x2 = sx2[li];
            float ar = (y2 - y1) * (x2 - x1);
            float ih = fmaxf(0.f, fminf(y2, cy2) - fmaxf(y1, cy1));
            float iw = fmaxf(0.f, fminf(x2, cx2) - fmaxf(x1, cx1));
            float inter = ih * iw;
            float uni = (ar + car) - inter;
            bool s = (inter > 0.f) && (inter / uni > 0.5f);
            uint64_t bal = __ballot(s);
            if (lane == 0 && bal) {
                int word = (sg * SEGSZ + k * 1024 + wv * 64) >> 6;
                sup[word] |= bal;
            }
        }
        __syncthreads();
    }

    if (tid == 0) cnt_out[b] = keptcnt_s;
    for (int i = tid; i < MAXD; i += 1024)
        kidx_out[b * MAXD + i] = (i < keptcnt_s) ? keptidx[i] : 0;
}

extern "C" void kernel_launch(void* const* d_in, const int* in_sizes, int n_in,
                              void* d_out, int out_size, void* d_ws, size_t ws_size,
                              hipStream_t stream) {
    const float* boxes = (const float*)d_in[0];   // [B,N,4]
    const float* cls   = (const float*)d_in[1];   // [B,N,C]
    float* out = (float*)d_out;
    float* out_box = out;                                                  // [B,100,4]
    float* out_cls = out + (size_t)BB * MAXD * 4;                          // [B,100,80]
    float* probs   = out + (size_t)BB * MAXD * 4 + (size_t)BB * MAXD * CC; // [B,N,80]

    char* ws = (char*)d_ws;
    uint64_t* keys = (uint64_t*)(ws + WS_KEYS);

    k_softmax<<<(BB * NN * 8) / 256, 256, 0, stream>>>(cls, probs, keys);

    if (ws_size >= (size_t)WS_NEED) {
        k_pnms<<<BB, 1024, 0, stream>>>(keys, boxes, probs, out_box, out_cls);
    } else {
        int* kidx = (int*)(ws + (size_t)BB * NN * sizeof(uint64_t));
        int* cnt  = kidx + BB * MAXD;
        k_nms_fb<<<BB, 1024, 0, stream>>>(keys, boxes, kidx, cnt);
        k_gather<<<(BB * PER_B + 255) / 256, 256, 0, stream>>>(boxes, probs, kidx, cnt,
                                                               out_box, out_cls);
    }
}